// Round 1
// baseline (373.493 us; speedup 1.0000x reference)
//
#include <hip/hip_runtime.h>
#include <hip/hip_fp16.h>

typedef _Float16 f16;
typedef _Float16 f16x4_t __attribute__((ext_vector_type(4)));
typedef _Float16 f16x8_t __attribute__((ext_vector_type(8)));
typedef float    f32x4_t __attribute__((ext_vector_type(4)));

#define NB  4
#define NC  256
#define NH  256
#define NW  256
#define NQ  256   // 16*16 pooled positions

// ---------------- kernel 1: convert weights (f,g,h) to f16, row-major [cout][ch] ----
__global__ __launch_bounds__(256) void k_convert_w(
    const float* __restrict__ f_w, const float* __restrict__ g_w,
    const float* __restrict__ h_w, f16* __restrict__ wf)
{
    int id = blockIdx.x * 256 + threadIdx.x;   // 0 .. 131071  (512*256)
    int cout = id >> 8;
    float v;
    if (cout < 128)       v = f_w[id];
    else if (cout < 256)  v = g_w[id - 128*256];
    else                  v = h_w[id - 256*256];
    wf[id] = (f16)v;
}

// ---------------- kernel 2: fused conv1x1 (512 couts) + 16x16 maxpool ----------------
// grid: 1024 = B * 256 windows; block: 512 threads (8 waves)
// waves 0..3 -> couts 0..255 (f,g) : 2-pass f16 (hi+lo) for precision
// waves 4..7 -> couts 256..511 (h) : 1-pass f16
__global__ __launch_bounds__(512) void k_pooled_conv(
    const float* __restrict__ x, const f16* __restrict__ wf,
    const float* __restrict__ f_b, const float* __restrict__ g_b,
    const float* __restrict__ h_b,
    float* __restrict__ pooled_fg,   // [B][256][NQ]
    float* __restrict__ pooledT_h)   // [B][NQ][256]
{
    __shared__ f16 Xh[64 * 256];   // quarter-window [pos 64][ch 256], swizzled
    __shared__ f16 Xl[64 * 256];

    const int blk  = blockIdx.x;
    const int b    = blk >> 8;
    const int win  = blk & 255;
    const int wi   = win >> 4;
    const int wj   = win & 15;
    const int t    = threadIdx.x;
    const int wave = t >> 6;
    const int lane = t & 63;
    const int l15  = lane & 15;
    const int lg   = lane >> 4;
    const bool fg  = (wave < 4);

    // preload B fragments (weights): wave covers couts [wave*64, wave*64+64)
    // B-frag lane layout: col n = lane&15, k = (lane>>4)*8 + j  -> 16B contiguous in [cout][ch]
    f16x8_t bfrag[4][8];
    #pragma unroll
    for (int n = 0; n < 4; n++) {
        const f16* wr = wf + (wave*64 + n*16 + l15) * 256 + lg*8;
        #pragma unroll
        for (int k = 0; k < 8; k++)
            bfrag[n][k] = *(const f16x8_t*)(wr + k*32);
    }

    float vmax[4] = {-1e30f, -1e30f, -1e30f, -1e30f};

    const float* xb = x + (size_t)b * NC * (NH*NW) + (wi*16)*NW + wj*16;

    for (int st = 0; st < 4; st++) {
        __syncthreads();   // protect LDS from readers of previous stage
        // ---- stage quarter window: pos p = st*64 + pl (dy = st*4 + pl/16, dx = pl%16) ----
        #pragma unroll
        for (int it = 0; it < 2; it++) {
            int s   = it*512 + t;       // 0..1023 tiles of 4pos x 4ch
            int pt  = s & 15;
            int ct  = s >> 4;           // 0..63
            int pl0 = pt * 4;
            int c0  = ct * 4;
            int dy  = st*4 + (pl0 >> 4);
            int dx  = pl0 & 15;
            const float* src = xb + (size_t)c0*(NH*NW) + dy*NW + dx;
            float4 r0 = *(const float4*)(src);
            float4 r1 = *(const float4*)(src +     NH*NW);
            float4 r2 = *(const float4*)(src + 2*(NH*NW));
            float4 r3 = *(const float4*)(src + 3*(NH*NW));
            float col[4][4] = {{r0.x,r1.x,r2.x,r3.x},{r0.y,r1.y,r2.y,r3.y},
                               {r0.z,r1.z,r2.z,r3.z},{r0.w,r1.w,r2.w,r3.w}};
            #pragma unroll
            for (int qq = 0; qq < 4; qq++) {
                int pl = pl0 + qq;
                unsigned off = ((unsigned)(pl*256 + c0) * 2u) ^ ((unsigned)(pl & 31) << 4);
                f16x4_t hv, lv;
                #pragma unroll
                for (int r = 0; r < 4; r++) {
                    float v = col[qq][r];
                    f16 hi  = (f16)v;
                    hv[r] = hi;
                    lv[r] = (f16)(v - (float)hi);
                }
                *(f16x4_t*)((char*)Xh + off) = hv;
                *(f16x4_t*)((char*)Xl + off) = lv;
            }
        }
        __syncthreads();
        // ---- MFMA: D[pos][cout] += X[pos][ch] * W[cout][ch] ----
        #pragma unroll
        for (int m = 0; m < 4; m++) {
            f32x4_t acc[4] = {{0.f,0.f,0.f,0.f},{0.f,0.f,0.f,0.f},
                              {0.f,0.f,0.f,0.f},{0.f,0.f,0.f,0.f}};
            #pragma unroll
            for (int k = 0; k < 8; k++) {
                int pos = m*16 + l15;                      // A row = lane&15
                unsigned off = ((unsigned)(pos*256 + k*32 + lg*8) * 2u)
                             ^ ((unsigned)(pos & 31) << 4);
                f16x8_t ah = *(const f16x8_t*)((const char*)Xh + off);
                if (fg) {
                    f16x8_t al = *(const f16x8_t*)((const char*)Xl + off);
                    #pragma unroll
                    for (int n = 0; n < 4; n++) {
                        acc[n] = __builtin_amdgcn_mfma_f32_16x16x32_f16(ah, bfrag[n][k], acc[n], 0, 0, 0);
                        acc[n] = __builtin_amdgcn_mfma_f32_16x16x32_f16(al, bfrag[n][k], acc[n], 0, 0, 0);
                    }
                } else {
                    #pragma unroll
                    for (int n = 0; n < 4; n++)
                        acc[n] = __builtin_amdgcn_mfma_f32_16x16x32_f16(ah, bfrag[n][k], acc[n], 0, 0, 0);
                }
            }
            #pragma unroll
            for (int n = 0; n < 4; n++)
                #pragma unroll
                for (int r = 0; r < 4; r++)
                    vmax[n] = fmaxf(vmax[n], acc[n][r]);   // max over pos rows (lane>>4)*4+r
        }
    }

    // combine partial maxes across pos-row groups (lane bits 4,5)
    #pragma unroll
    for (int n = 0; n < 4; n++) {
        float v = vmax[n];
        v = fmaxf(v, __shfl_xor(v, 16, 64));
        v = fmaxf(v, __shfl_xor(v, 32, 64));
        vmax[n] = v;
    }
    if (lane < 16) {
        #pragma unroll
        for (int n = 0; n < 4; n++) {
            int cout = wave*64 + n*16 + lane;
            float bias = (cout < 128) ? f_b[cout]
                       : (cout < 256) ? g_b[cout - 128]
                                      : h_b[cout - 256];
            float val = vmax[n] + bias;
            if (cout < 256) pooled_fg[((b*256 + cout) << 8) + win] = val;
            else            pooledT_h[((b*256 + win)  << 8) + (cout - 256)] = val;
        }
    }
}

// ---------------- kernel 3: dots + softmax + PV (all fp32) ----------------
// grid: 1024 = B * 256 queries; block: 256 threads (thread = key idx, then thread = cout)
__global__ __launch_bounds__(256) void k_attn(
    const float* __restrict__ pooled_fg, const float* __restrict__ pooledT_h,
    float* __restrict__ attnout)   // [B][256][NQ]
{
    __shared__ float red[4];
    __shared__ float p_lds[256];
    const int blk = blockIdx.x;
    const int b = blk >> 8;
    const int q = blk & 255;
    const int t = threadIdx.x;

    const float* fv = pooled_fg + ((b*256) << 8) + q;         // fv[c][q]
    const float* gv = pooled_fg + ((b*256 + 128) << 8) + t;   // gv[c][t]

    float s = 0.f;
    #pragma unroll 8
    for (int c = 0; c < 128; c++)
        s += fv[c << 8] * gv[c << 8];

    // block-wide max
    float m = s;
    #pragma unroll
    for (int o = 1; o < 64; o <<= 1) m = fmaxf(m, __shfl_xor(m, o, 64));
    if ((t & 63) == 0) red[t >> 6] = m;
    __syncthreads();
    m = fmaxf(fmaxf(red[0], red[1]), fmaxf(red[2], red[3]));
    __syncthreads();   // before reusing red[]

    float p = expf(s - m);
    float sum = p;
    #pragma unroll
    for (int o = 1; o < 64; o <<= 1) sum += __shfl_xor(sum, o, 64);
    if ((t & 63) == 0) red[t >> 6] = sum;
    __syncthreads();
    sum = red[0] + red[1] + red[2] + red[3];
    p /= sum;
    p_lds[t] = p;
    __syncthreads();

    // out[c=t, q] = sum_k p[k] * hv[c][k]   with hv stored transposed [k][c] -> coalesced
    const float* hv = pooledT_h + (b << 16) + t;
    float acc = 0.f;
    #pragma unroll 8
    for (int k = 0; k < 256; k++)
        acc += p_lds[k] * hv[k << 8];
    attnout[((b*256 + t) << 8) + q] = acc;
}

// ---------------- kernel 4: bilinear 16x upsample (half-pixel, edge-clamped) + x ----
// grid: 1024 = B*C planes; block 256 threads
__global__ __launch_bounds__(256) void k_upsample_add(
    const float* __restrict__ x, const float* __restrict__ attnout,
    float* __restrict__ out)
{
    __shared__ float L[256];   // the 16x16 plane
    const int blk = blockIdx.x;            // b*256 + c
    const int t = threadIdx.x;
    L[t] = attnout[(blk << 8) + t];
    __syncthreads();
    const float* xp = x   + (size_t)blk * 65536;
    float*       op = out + (size_t)blk * 65536;
    for (int it = 0; it < 64; it++) {
        int idx4 = it*256 + t;
        int y  = idx4 >> 6;
        int x4 = (idx4 & 63) << 2;
        float sy  = (y + 0.5f) * 0.0625f - 0.5f;
        float y0f = floorf(sy);
        float fy  = sy - y0f;
        int iy0 = (int)y0f;
        int y0 = min(15, max(0, iy0));
        int y1 = min(15, max(0, iy0 + 1));
        const float* Ly0 = L + y0*16;
        const float* Ly1 = L + y1*16;
        float4 xin = *(const float4*)(xp + y*256 + x4);
        float o[4]; const float* xe = (const float*)&xin;
        #pragma unroll
        for (int e = 0; e < 4; e++) {
            int xx = x4 + e;
            float sx  = (xx + 0.5f) * 0.0625f - 0.5f;
            float x0f = floorf(sx);
            float fx  = sx - x0f;
            int ix0 = (int)x0f;
            int x0i = min(15, max(0, ix0));
            int x1i = min(15, max(0, ix0 + 1));
            float top = Ly0[x0i] + fx * (Ly0[x1i] - Ly0[x0i]);
            float bot = Ly1[x0i] + fx * (Ly1[x1i] - Ly1[x0i]);
            o[e] = top + fy * (bot - top) + xe[e];
        }
        float4 ov = make_float4(o[0], o[1], o[2], o[3]);
        *(float4*)(op + y*256 + x4) = ov;
    }
}

extern "C" void kernel_launch(void* const* d_in, const int* in_sizes, int n_in,
                              void* d_out, int out_size, void* d_ws, size_t ws_size,
                              hipStream_t stream)
{
    const float* x   = (const float*)d_in[0];
    const float* f_w = (const float*)d_in[1];
    const float* f_b = (const float*)d_in[2];
    const float* g_w = (const float*)d_in[3];
    const float* g_b = (const float*)d_in[4];
    const float* h_w = (const float*)d_in[5];
    const float* h_b = (const float*)d_in[6];
    float* out = (float*)d_out;

    char* ws = (char*)d_ws;
    f16*   wf        = (f16*)ws;                              // 256 KB
    float* pooled_fg = (float*)(ws + (256<<10));              // 1 MB  [B][256][NQ]
    float* pooledT_h = (float*)(ws + (256<<10) + (1<<20));    // 1 MB  [B][NQ][256]
    float* attnout   = (float*)(ws + (256<<10) + (2<<20));    // 1 MB  [B][256][NQ]

    k_convert_w  <<<512, 256, 0, stream>>>(f_w, g_w, h_w, wf);
    k_pooled_conv<<<1024, 512, 0, stream>>>(x, wf, f_b, g_b, h_b, pooled_fg, pooledT_h);
    k_attn       <<<1024, 256, 0, stream>>>(pooled_fg, pooledT_h, attnout);
    k_upsample_add<<<1024, 256, 0, stream>>>(x, attnout, out);
}

// Round 2
// 283.850 us; speedup vs baseline: 1.3158x; 1.3158x over previous
//
#include <hip/hip_runtime.h>
#include <hip/hip_fp16.h>

typedef _Float16 f16;
typedef _Float16 f16x2_t __attribute__((ext_vector_type(2)));
typedef _Float16 f16x8_t __attribute__((ext_vector_type(8)));
typedef float    f32x4_t __attribute__((ext_vector_type(4)));

#define NB  4
#define NC  256
#define NH  256
#define NW  256

// ---------------- kernel 1: convert weights (f,g,h) to f16, row-major [cout][ch] ----
__global__ __launch_bounds__(256) void k_convert_w(
    const float* __restrict__ f_w, const float* __restrict__ g_w,
    const float* __restrict__ h_w, f16* __restrict__ wf)
{
    int id = blockIdx.x * 256 + threadIdx.x;   // 0 .. 131071  (512*256)
    int cout = id >> 8;
    float v;
    if (cout < 128)       v = f_w[id];
    else if (cout < 256)  v = g_w[id - 128*256];
    else                  v = h_w[id - 256*256];
    wf[id] = (f16)v;
}

// ---------------- kernel 2: fused conv1x1 (512 couts) + 16x16 maxpool ----------------
// Persistent pipeline: 256 blocks x 1024 threads (16 waves), 4 windows/block,
// 8 stages of 32 pos per window, double-buffered LDS, 1 barrier/stage,
// global loads issued 2 stages ahead (reg-staged: fp32 -> f16 hi/lo split).
// Waves 0..7: couts 0..255 (f,g), 2-pass hi/lo f16. Waves 8..15: couts 256..511 (h), 1-pass.
// LDS fragment-order layout: element (pos 0..31, ch 0..255) at
//   byte = ((pos>>4)*8 + (ch>>5))<<10  +  g(pos&15, (ch>>3)&3)*16 + (ch&7)*2
//   g(l15,lg) = (l15>>2) | ((lg&1)<<2) | ((l15&3)<<3) | ((lg>>1)<<5)   (bijective 0..63)
// => every ds_read_b128 A-fragment is lane-linear (0 conflicts); writes hit 32 banks 2-way.
__global__ __launch_bounds__(1024, 4) void k_pooled_conv(
    const float* __restrict__ x, const f16* __restrict__ wf,
    const float* __restrict__ f_b, const float* __restrict__ g_b,
    const float* __restrict__ h_b,
    float* __restrict__ pooled_fg,   // [B][256][256]
    float* __restrict__ pooledT_h)   // [B][256][256]
{
    __shared__ __align__(16) char smem[65536];  // [buf2][hi/lo 16KB each]

    const int t    = threadIdx.x;
    const int wave = t >> 6;
    const int lane = t & 63;
    const int l15  = lane & 15;
    const int lg   = lane >> 4;
    const bool isfg = (wave < 8);
    const int coutbase = isfg ? wave * 32 : 256 + (wave - 8) * 32;

    // ---- weight fragments: wave covers 32 couts (2 x 16) ----
    f16x8_t bfrag[2][8];
    #pragma unroll
    for (int nn = 0; nn < 2; nn++) {
        const f16* wr = wf + (coutbase + nn*16 + l15) * 256 + lg*8;
        #pragma unroll
        for (int k = 0; k < 8; k++)
            bfrag[nn][k] = *(const f16x8_t*)(wr + k*32);
    }
    float biasv[2];
    #pragma unroll
    for (int nn = 0; nn < 2; nn++) {
        int c = coutbase + nn*16 + l15;
        biasv[nn] = (c < 128) ? f_b[c] : (c < 256) ? g_b[c - 128] : h_b[c - 256];
    }

    // ---- staging thread coords: thread owns 4 pos x 2 ch ----
    const int ct  = t >> 3;           // 0..127
    const int c0  = ct * 2;
    const int pt  = t & 7;
    const int pl0 = pt * 4;           // pos base 0..28
    const int sm  = pt >> 2;          // m-tile of these pos
    const int kw  = c0 >> 5, lgw = (c0 >> 3) & 3, jw = c0 & 7;
    unsigned woff[4];
    #pragma unroll
    for (int w = 0; w < 4; w++) {
        int p15 = (pl0 & 15) + w;
        unsigned g = (unsigned)((p15 >> 2) | ((lgw & 1) << 2) | ((p15 & 3) << 3) | ((lgw >> 1) << 5));
        woff[w] = ((unsigned)(sm * 8 + kw) << 10) + g * 16 + (unsigned)jw * 2;
    }
    const unsigned rdg =
        (unsigned)((l15 >> 2) | ((lg & 1) << 2) | ((l15 & 3) << 3) | ((lg >> 1) << 5)) * 16u;

    const int bid   = blockIdx.x;
    const int b     = bid >> 6;
    const int wbase = bid * 4;        // 4 consecutive windows
    const float* xb = x + (size_t)b * (256u * 65536u);
    const int dyl = pl0 >> 4;         // 0/1 within stage's 2 rows
    const int dxl = pl0 & 15;

    float vmax[2] = {-3.0e38f, -3.0e38f};

    auto loadst = [&](int gsd, float4& A0, float4& A1) {
        int win = wbase + (gsd >> 3);
        int s   = gsd & 7;
        int wi = (win >> 4) & 15, wj = win & 15;
        const float* src = xb + (size_t)c0 * 65536u
                         + (unsigned)((wi*16 + s*2 + dyl) * 256 + wj*16 + dxl);
        A0 = *(const float4*)src;
        A1 = *(const float4*)(src + 65536);
    };
    auto writest = [&](const float4& A0, const float4& A1, int buf) {
        char* base = smem + buf * 32768;
        const float* a0 = (const float*)&A0;
        const float* a1 = (const float*)&A1;
        #pragma unroll
        for (int w = 0; w < 4; w++) {
            float v0 = a0[w], v1 = a1[w];
            f16 h0 = (f16)v0, h1 = (f16)v1;
            f16x2_t hv = {h0, h1};
            f16x2_t lv = {(f16)(v0 - (float)h0), (f16)(v1 - (float)h1)};
            *(f16x2_t*)(base + woff[w])         = hv;
            *(f16x2_t*)(base + 16384 + woff[w]) = lv;
        }
    };
    auto mfmast = [&](int buf) {
        const char* base = smem + buf * 32768;
        if (isfg) {
            #pragma unroll
            for (int m = 0; m < 2; m++) {
                f32x4_t acc0 = {0.f,0.f,0.f,0.f}, acc1 = {0.f,0.f,0.f,0.f};
                #pragma unroll
                for (int k = 0; k < 8; k++) {
                    const char* p = base + ((m*8 + k) << 10) + rdg;
                    f16x8_t ah = *(const f16x8_t*)p;
                    f16x8_t al = *(const f16x8_t*)(p + 16384);
                    acc0 = __builtin_amdgcn_mfma_f32_16x16x32_f16(ah, bfrag[0][k], acc0, 0,0,0);
                    acc1 = __builtin_amdgcn_mfma_f32_16x16x32_f16(ah, bfrag[1][k], acc1, 0,0,0);
                    acc0 = __builtin_amdgcn_mfma_f32_16x16x32_f16(al, bfrag[0][k], acc0, 0,0,0);
                    acc1 = __builtin_amdgcn_mfma_f32_16x16x32_f16(al, bfrag[1][k], acc1, 0,0,0);
                }
                #pragma unroll
                for (int r = 0; r < 4; r++) {
                    vmax[0] = fmaxf(vmax[0], acc0[r]);
                    vmax[1] = fmaxf(vmax[1], acc1[r]);
                }
            }
        } else {
            #pragma unroll
            for (int m = 0; m < 2; m++) {
                f32x4_t acc0 = {0.f,0.f,0.f,0.f}, acc1 = {0.f,0.f,0.f,0.f};
                #pragma unroll
                for (int k = 0; k < 8; k++) {
                    const char* p = base + ((m*8 + k) << 10) + rdg;
                    f16x8_t ah = *(const f16x8_t*)p;
                    acc0 = __builtin_amdgcn_mfma_f32_16x16x32_f16(ah, bfrag[0][k], acc0, 0,0,0);
                    acc1 = __builtin_amdgcn_mfma_f32_16x16x32_f16(ah, bfrag[1][k], acc1, 0,0,0);
                }
                #pragma unroll
                for (int r = 0; r < 4; r++) {
                    vmax[0] = fmaxf(vmax[0], acc0[r]);
                    vmax[1] = fmaxf(vmax[1], acc1[r]);
                }
            }
        }
    };
    auto finalize = [&](int win) {
        int wn = win & 255;
        #pragma unroll
        for (int nn = 0; nn < 2; nn++) {
            float v = vmax[nn];
            v = fmaxf(v, __shfl_xor(v, 16, 64));
            v = fmaxf(v, __shfl_xor(v, 32, 64));
            if (lane < 16) {
                float val = v + biasv[nn];
                int c = coutbase + nn*16 + lane;
                if (isfg) pooled_fg[((b*256 + c)  << 8) + wn] = val;
                else      pooledT_h[((b*256 + wn) << 8) + (c - 256)] = val;
            }
            vmax[nn] = -3.0e38f;
        }
    };

    // ---- pipeline: 32 global stages (4 windows x 8) ----
    float4 rA0, rA1, rB0, rB1;
    loadst(0, rA0, rA1);
    writest(rA0, rA1, 0);
    loadst(1, rB0, rB1);
    __syncthreads();

    #pragma unroll 1
    for (int gs = 0; gs < 32; gs += 2) {
        // even stage gs : compute buf0, write stage gs+1 -> buf1, load gs+2 -> A
        if (gs + 2 < 32) loadst(gs + 2, rA0, rA1);
        writest(rB0, rB1, 1);
        mfmast(0);
        __syncthreads();
        // odd stage gs+1 : compute buf1, write stage gs+2 -> buf0, load gs+3 -> B
        if (gs + 3 < 32) loadst(gs + 3, rB0, rB1);
        if (gs + 2 < 32) writest(rA0, rA1, 0);
        mfmast(1);
        if ((gs & 7) == 6) finalize(wbase + (gs >> 3));
        __syncthreads();
    }
}

// ---------------- kernel 3: dots + softmax + PV (all fp32) ----------------
__global__ __launch_bounds__(256) void k_attn(
    const float* __restrict__ pooled_fg, const float* __restrict__ pooledT_h,
    float* __restrict__ attnout)   // [B][256][256]
{
    __shared__ float red[4];
    __shared__ float p_lds[256];
    const int blk = blockIdx.x;
    const int b = blk >> 8;
    const int q = blk & 255;
    const int t = threadIdx.x;

    const float* fv = pooled_fg + ((b*256) << 8) + q;         // fv[c][q]
    const float* gv = pooled_fg + ((b*256 + 128) << 8) + t;   // gv[c][t]

    float s = 0.f;
    #pragma unroll 8
    for (int c = 0; c < 128; c++)
        s += fv[c << 8] * gv[c << 8];

    float m = s;
    #pragma unroll
    for (int o = 1; o < 64; o <<= 1) m = fmaxf(m, __shfl_xor(m, o, 64));
    if ((t & 63) == 0) red[t >> 6] = m;
    __syncthreads();
    m = fmaxf(fmaxf(red[0], red[1]), fmaxf(red[2], red[3]));
    __syncthreads();

    float p = expf(s - m);
    float sum = p;
    #pragma unroll
    for (int o = 1; o < 64; o <<= 1) sum += __shfl_xor(sum, o, 64);
    if ((t & 63) == 0) red[t >> 6] = sum;
    __syncthreads();
    sum = red[0] + red[1] + red[2] + red[3];
    p /= sum;
    p_lds[t] = p;
    __syncthreads();

    const float* hv = pooledT_h + (b << 16) + t;
    float acc = 0.f;
    #pragma unroll 8
    for (int k = 0; k < 256; k++)
        acc += p_lds[k] * hv[k << 8];
    attnout[((b*256 + t) << 8) + q] = acc;
}

// ---------------- kernel 4: bilinear 16x upsample (half-pixel, edge-clamped) + x ----
__global__ __launch_bounds__(256) void k_upsample_add(
    const float* __restrict__ x, const float* __restrict__ attnout,
    float* __restrict__ out)
{
    __shared__ float L[256];
    const int blk = blockIdx.x;            // b*256 + c
    const int t = threadIdx.x;
    L[t] = attnout[(blk << 8) + t];
    __syncthreads();
    const float* xp = x   + (size_t)blk * 65536;
    float*       op = out + (size_t)blk * 65536;

    const int x4 = (t & 63) << 2;
    const int yo = t >> 6;
    float fxv[4]; int x0v[4], x1v[4];
    #pragma unroll
    for (int e = 0; e < 4; e++) {
        float sx  = (x4 + e + 0.5f) * 0.0625f - 0.5f;
        float x0f = floorf(sx);
        fxv[e] = sx - x0f;
        int ix0 = (int)x0f;
        x0v[e] = min(15, max(0, ix0));
        x1v[e] = min(15, max(0, ix0 + 1));
    }
    for (int it = 0; it < 64; it++) {
        int y = it*4 + yo;
        float sy  = (y + 0.5f) * 0.0625f - 0.5f;
        float y0f = floorf(sy);
        float fy  = sy - y0f;
        int iy0 = (int)y0f;
        int y0 = min(15, max(0, iy0));
        int y1 = min(15, max(0, iy0 + 1));
        const float* Ly0 = L + y0*16;
        const float* Ly1 = L + y1*16;
        float4 xin = *(const float4*)(xp + y*256 + x4);
        float o[4]; const float* xe = (const float*)&xin;
        #pragma unroll
        for (int e = 0; e < 4; e++) {
            float top = Ly0[x0v[e]] + fxv[e] * (Ly0[x1v[e]] - Ly0[x0v[e]]);
            float bot = Ly1[x0v[e]] + fxv[e] * (Ly1[x1v[e]] - Ly1[x0v[e]]);
            o[e] = top + fy * (bot - top) + xe[e];
        }
        float4 ov = make_float4(o[0], o[1], o[2], o[3]);
        *(float4*)(op + y*256 + x4) = ov;
    }
}

extern "C" void kernel_launch(void* const* d_in, const int* in_sizes, int n_in,
                              void* d_out, int out_size, void* d_ws, size_t ws_size,
                              hipStream_t stream)
{
    const float* x   = (const float*)d_in[0];
    const float* f_w = (const float*)d_in[1];
    const float* f_b = (const float*)d_in[2];
    const float* g_w = (const float*)d_in[3];
    const float* g_b = (const float*)d_in[4];
    const float* h_w = (const float*)d_in[5];
    const float* h_b = (const float*)d_in[6];
    float* out = (float*)d_out;

    char* ws = (char*)d_ws;
    f16*   wf        = (f16*)ws;                              // 256 KB
    float* pooled_fg = (float*)(ws + (256<<10));              // 1 MB  [B][256][256]
    float* pooledT_h = (float*)(ws + (256<<10) + (1<<20));    // 1 MB  [B][256][256]
    float* attnout   = (float*)(ws + (256<<10) + (2<<20));    // 1 MB  [B][256][256]

    k_convert_w   <<<512, 256, 0, stream>>>(f_w, g_w, h_w, wf);
    k_pooled_conv <<<256, 1024, 0, stream>>>(x, wf, f_b, g_b, h_b, pooled_fg, pooledT_h);
    k_attn        <<<1024, 256, 0, stream>>>(pooled_fg, pooledT_h, attnout);
    k_upsample_add<<<1024, 256, 0, stream>>>(x, attnout, out);
}